// Round 8
// baseline (4191.702 us; speedup 1.0000x reference)
//
#include <hip/hip_runtime.h>
#include <hip/hip_bf16.h>
#include <stdint.h>

typedef unsigned int u32;
typedef unsigned short u16;

#define F 128

typedef __attribute__((ext_vector_type(8))) short bf16x8;
typedef __attribute__((ext_vector_type(4))) float f32x4;

__device__ __forceinline__ float bf2f(u16 v){
  union { u32 u; float f; } x; x.u = ((u32)v) << 16; return x.f;
}
__device__ __forceinline__ u16 f2bf(float f){
  union { float f; u32 u; } x; x.f = f;
  u32 u = x.u;
  return (u16)((u + 0x7fffu + ((u >> 16) & 1u)) >> 16);   // RNE
}

// flags[0]=edge-int32 flag, flags[1]=x-is-f32 flag; also zeroes bcnt.
__global__ void k_flags(const u32* __restrict__ x, const u32* __restrict__ ei,
                        int* __restrict__ flags, int* __restrict__ bcnt){
  __shared__ int f[2];
  int t = threadIdx.x;
  bcnt[t] = 0;
  if (t < 2) f[t] = 0;
  __syncthreads();
  int hit = 0;
  for (int i = t; i < 2048; i += 256){
    u32 e = (x[i] >> 7) & 0xFFu;          // f32 words: uniform bits[14:7]
    if (e > 160u) hit = 1;                // bf16-pair data never exceeds 160
  }
  if (hit) atomicOr(&f[1], 1);
  u32 v = 0;
  for (int i = t; i < 4096; i += 256) v |= ei[2*i + 1];  // int64 ids<50000 -> odd words 0
  if (v) atomicOr(&f[0], 1);
  __syncthreads();
  if (t < 2) flags[t] = f[t];
}

// ---- bucketed edge build (256-node dst buckets) -----------------------------
__launch_bounds__(256)
__global__ void k_bhist(const u32* __restrict__ w, int E, const int* __restrict__ flagp,
                        int NB, int* __restrict__ bcnt){
  __shared__ int h[256];
  int st = (*flagp) ? 1 : 2;
  int t = threadIdx.x;
  h[t] = 0;
  __syncthreads();
  int base = blockIdx.x*4096;
  #pragma unroll 4
  for (int k = 0; k < 16; k++){
    int i = base + k*256 + t;
    if (i < E){
      int d = (int)w[(size_t)(E + i)*st];
      atomicAdd(&h[d >> 8], 1);
    }
  }
  __syncthreads();
  if (t < NB && h[t]) atomicAdd(&bcnt[t], h[t]);
}

__global__ void k_bscan(const int* __restrict__ bcnt, int NB, int E,
                        int* __restrict__ bbase, int* __restrict__ bump){
  __shared__ int s[256];
  int t = threadIdx.x;
  int v = (t < NB) ? bcnt[t] : 0;
  s[t] = v;
  __syncthreads();
  for (int off = 1; off < 256; off <<= 1){
    int x = (t >= off) ? s[t - off] : 0;
    __syncthreads();
    s[t] += x;
    __syncthreads();
  }
  bbase[t] = s[t] - v;            // exclusive; == E for t >= NB
  if (t == 255) bbase[256] = E;
  bump[t] = 0;
}

__launch_bounds__(256)
__global__ void k_msplit(const u32* __restrict__ w, int E, const int* __restrict__ flagp,
                         const int* __restrict__ bbase, int* __restrict__ bump,
                         u32* __restrict__ ebuf){
  __shared__ int h[256];
  __shared__ int cb[256];
  int st = (*flagp) ? 1 : 2;
  int t = threadIdx.x;
  h[t] = 0;
  __syncthreads();
  int base = blockIdx.x*4096;
  u32 ps[16]; int bk[16]; int rk[16];
  #pragma unroll 4
  for (int k = 0; k < 16; k++){
    int i = base + k*256 + t;
    if (i < E){
      u32 s = w[(size_t)i*st];
      u32 d = w[(size_t)(E + i)*st];
      bk[k] = (int)(d >> 8);
      ps[k] = (s & 0xFFFFu) | ((d & 0xFFu) << 16);
      rk[k] = atomicAdd(&h[bk[k]], 1);
    } else bk[k] = -1;
  }
  __syncthreads();
  cb[t] = h[t] ? (bbase[t] + atomicAdd(&bump[t], h[t])) : 0;
  __syncthreads();
  #pragma unroll 4
  for (int k = 0; k < 16; k++){
    if (bk[k] >= 0) ebuf[cb[bk[k]] + rk[k]] = ps[k];
  }
}

// Per-bucket degree histogram -> dis; zero g4. No scan/scatter/CSR needed.
__global__ void k_bemit(const u32* __restrict__ ebuf, const int* __restrict__ bbase,
                        int N, float* __restrict__ dis, float* __restrict__ g4){
  __shared__ int h[256];
  int b = blockIdx.x, t = threadIdx.x;
  int e0 = bbase[b], e1 = bbase[b + 1];
  h[t] = 0;
  __syncthreads();
  for (int i = e0 + t; i < e1; i += 256) atomicAdd(&h[(ebuf[i] >> 16) & 0xFFu], 1);
  __syncthreads();
  int n = b*256 + t;
  if (n < N){
    dis[n] = rsqrtf(1.0f + (float)h[t]);
    g4[n]  = 0.f;
  }
}

// One-shot weight prep: 3x swizzled W (MFMA B-frag order) + 3 biases + W4 + b4.
__global__ void k_prep(const void* __restrict__ W1, const void* __restrict__ W2,
                       const void* __restrict__ W3, const void* __restrict__ W4,
                       const void* __restrict__ b1, const void* __restrict__ b2,
                       const void* __restrict__ b3, const void* __restrict__ b4,
                       const int* __restrict__ isf32, u16* __restrict__ WL,
                       float* __restrict__ bb, float* __restrict__ wf4,
                       float* __restrict__ bb4){
  int b = blockIdx.x, t = threadIdx.x;
  int f32 = *isf32;
  if (b < 192){
    int l = b >> 6;
    const void* W = (l == 0) ? W1 : (l == 1) ? W2 : W3;
    int idx = (b & 63)*256 + t;          // 0..16383
    int j    = idx & 7;
    int lane = (idx >> 3) & 63;
    int kb   = (idx >> 9) & 3;
    int ct   = idx >> 11;
    int m = lane & 15, q = lane >> 4;
    int k = kb*32 + q*8 + j;
    int c = ct*16 + m;
    float v = f32 ? ((const float*)W)[k*F + c] : bf2f(((const u16*)W)[k*F + c]);
    WL[l*16384 + idx] = f2bf(v);
  } else {
    if (t < 128){
      const void* bs[3] = {b1, b2, b3};
      #pragma unroll
      for (int l = 0; l < 3; l++)
        bb[l*F + t] = f32 ? ((const float*)bs[l])[t] : bf2f(((const u16*)bs[l])[t]);
      wf4[t] = f32 ? ((const float*)W4)[t] : bf2f(((const u16*)W4)[t]);
      if (t == 0) bb4[0] = f32 ? ((const float*)b4)[0] : bf2f(((const u16*)b4)[0]);
    }
  }
}

// G = dis * (X @ W) stored as 4 contiguous planes (plane = 32 feats x Npad rows,
// 64 B/row, 3.2 MB). Rows [N, Npad) zero-filled.
__launch_bounds__(256)
__global__ void k_mm(const void* __restrict__ Xv, const int* __restrict__ isf32,
                     int dual, const u16* __restrict__ WL,
                     const float* __restrict__ dis, u16* __restrict__ G,
                     int N, int Npad){
  int w = threadIdx.x >> 6, lane = threadIdx.x & 63;
  int m = lane & 15, q = lane >> 4;
  int row0 = blockIdx.x*64 + w*16;
  int arow = row0 + m;
  bool f32 = dual && (*isf32);
  bf16x8 a[4];
  if (arow < N){
    if (f32){
      const float* xp = (const float*)Xv + (size_t)arow*F;
      #pragma unroll
      for (int kb = 0; kb < 4; kb++){
        float4 v0 = *(const float4*)(xp + kb*32 + q*8);
        float4 v1 = *(const float4*)(xp + kb*32 + q*8 + 4);
        a[kb][0] = (short)f2bf(v0.x); a[kb][1] = (short)f2bf(v0.y);
        a[kb][2] = (short)f2bf(v0.z); a[kb][3] = (short)f2bf(v0.w);
        a[kb][4] = (short)f2bf(v1.x); a[kb][5] = (short)f2bf(v1.y);
        a[kb][6] = (short)f2bf(v1.z); a[kb][7] = (short)f2bf(v1.w);
      }
    } else {
      const u16* xp = (const u16*)Xv + (size_t)arow*F;
      #pragma unroll
      for (int kb = 0; kb < 4; kb++) a[kb] = *(const bf16x8*)(xp + kb*32 + q*8);
    }
  } else {
    #pragma unroll
    for (int kb = 0; kb < 4; kb++) a[kb] = (bf16x8){0,0,0,0,0,0,0,0};
  }
  f32x4 acc[8];
  #pragma unroll
  for (int ct = 0; ct < 8; ct++) acc[ct] = (f32x4){0.f,0.f,0.f,0.f};
  #pragma unroll
  for (int ct = 0; ct < 8; ct++){
    #pragma unroll
    for (int kb = 0; kb < 4; kb++){
      bf16x8 b = *(const bf16x8*)(WL + ((size_t)((ct*4 + kb)*64 + lane))*8);
      acc[ct] = __builtin_amdgcn_mfma_f32_16x16x32_bf16(a[kb], b, acc[ct], 0, 0, 0);
    }
  }
  size_t planeW = (size_t)Npad*32;       // u16 elements per plane
  int rbase = row0 + q*4;
  #pragma unroll
  for (int r = 0; r < 4; r++){
    int row = rbase + r;
    float dv = (row < N) ? dis[row] : 0.f;      // pad rows -> zeros
    #pragma unroll
    for (int ct = 0; ct < 8; ct++){
      int p = ct >> 1, h = ct & 1;
      G[p*planeW + (size_t)row*32 + h*16 + m] = f2bf(dv*acc[ct][r]);
    }
  }
}

// Edge-parallel bucket aggregation. Block = (bucket, plane); plane pinned to an
// XCD-pair via blockIdx%8 so the 3.2MB plane stays L2-resident. LDS f32 accum
// [256 nodes][33] (padded stride). 16 lanes/edge, 4 edges per gather inst,
// ds_add_f32 fire-and-forget (no dependency chain). Epilogue: thread = node.
template<int LAST>
__launch_bounds__(256)
__global__ void k_aggB(const u16* __restrict__ G, const float* __restrict__ dis,
                       const int* __restrict__ bbase, const u32* __restrict__ ebuf,
                       const float* __restrict__ bias, const float* __restrict__ wf4,
                       float* __restrict__ g4, u16* __restrict__ Xout,
                       int N, int NB, int Npad){
  __shared__ float acc[256*33];
  int b = blockIdx.x;
  int x = b & 7;
  int plane = x >> 1;
  int bucket = ((b >> 3) << 1) + (x & 1);
  if (bucket >= NB) return;
  int t = threadIdx.x;
  #pragma unroll
  for (int i = 0; i < 33; i++) acc[i*256 + t] = 0.f;
  __syncthreads();
  int e0 = bbase[bucket], e1 = bbase[bucket + 1];
  const u32* P = (const u32*)G + (size_t)plane*((size_t)Npad*16);
  int wave = t >> 6, lane = t & 63;
  int g = lane >> 4, w = lane & 15;
  int e = e0 + wave*4 + g;
  int nE = e1 - e0;
  int nfull = nE >> 6;                  // full 64-edge block iterations
  for (int it = 0; it < nfull; it++){
    u32 v0 = ebuf[e];
    u32 v1 = ebuf[e + 16];
    u32 v2 = ebuf[e + 32];
    u32 v3 = ebuf[e + 48];
    u32 w0 = P[(v0 & 0xFFFFu)*16 + w];
    u32 w1 = P[(v1 & 0xFFFFu)*16 + w];
    u32 w2 = P[(v2 & 0xFFFFu)*16 + w];
    u32 w3 = P[(v3 & 0xFFFFu)*16 + w];
    int d0 = ((v0 >> 16) & 0xFFu)*33 + 2*w;
    int d1 = ((v1 >> 16) & 0xFFu)*33 + 2*w;
    int d2 = ((v2 >> 16) & 0xFFu)*33 + 2*w;
    int d3 = ((v3 >> 16) & 0xFFu)*33 + 2*w;
    atomicAdd(&acc[d0],     __uint_as_float(w0 << 16));
    atomicAdd(&acc[d0 + 1], __uint_as_float(w0 & 0xFFFF0000u));
    atomicAdd(&acc[d1],     __uint_as_float(w1 << 16));
    atomicAdd(&acc[d1 + 1], __uint_as_float(w1 & 0xFFFF0000u));
    atomicAdd(&acc[d2],     __uint_as_float(w2 << 16));
    atomicAdd(&acc[d2 + 1], __uint_as_float(w2 & 0xFFFF0000u));
    atomicAdd(&acc[d3],     __uint_as_float(w3 << 16));
    atomicAdd(&acc[d3 + 1], __uint_as_float(w3 & 0xFFFF0000u));
    e += 64;
  }
  for (; e < e1; e += 16){              // tail
    u32 v = ebuf[e];
    u32 wd = P[(v & 0xFFFFu)*16 + w];
    int d = ((v >> 16) & 0xFFu)*33 + 2*w;
    atomicAdd(&acc[d],     __uint_as_float(wd << 16));
    atomicAdd(&acc[d + 1], __uint_as_float(wd & 0xFFFF0000u));
  }
  __syncthreads();
  int n = bucket*256 + t;
  if (n >= N) return;
  float dv = dis[n];
  const uint4* Sp = (const uint4*)P + (size_t)n*4;
  u32* Xw = (u32*)Xout + (size_t)n*64 + plane*16;
  float dot = 0.f;
  #pragma unroll
  for (int q = 0; q < 4; q++){
    uint4 sv = Sp[q];
    u32 ws[4] = {sv.x, sv.y, sv.z, sv.w};
    #pragma unroll
    for (int j2 = 0; j2 < 4; j2++){
      int j = q*4 + j2;
      float s0 = __uint_as_float(ws[j2] << 16);
      float s1 = __uint_as_float(ws[j2] & 0xFFFF0000u);
      float o0 = fmaf(dv, s0 + acc[t*33 + 2*j],     bias[plane*32 + 2*j]);
      float o1 = fmaf(dv, s1 + acc[t*33 + 2*j + 1], bias[plane*32 + 2*j + 1]);
      o0 = fmaxf(o0, 0.f); o1 = fmaxf(o1, 0.f);
      if (LAST){
        dot += o0*wf4[plane*32 + 2*j] + o1*wf4[plane*32 + 2*j + 1];
      } else {
        Xw[j] = (u32)f2bf(o0) | ((u32)f2bf(o1) << 16);
      }
    }
  }
  if (LAST) atomicAdd(&g4[n], dv*dot);
}

// Final aggregation, bucket-parallel: 256 edges/iter, LDS f32 accum per node.
__launch_bounds__(256)
__global__ void k_agg4B(const float* __restrict__ g4, const float* __restrict__ dis,
                        const int* __restrict__ bbase, const u32* __restrict__ ebuf,
                        const float* __restrict__ b4f, const int* __restrict__ isf32,
                        void* __restrict__ out, int N){
  __shared__ float a[256];
  int b = blockIdx.x, t = threadIdx.x;
  int e0 = bbase[b], e1 = bbase[b + 1];
  a[t] = 0.f;
  __syncthreads();
  for (int i = e0 + t; i < e1; i += 256){
    u32 v = ebuf[i];
    atomicAdd(&a[(v >> 16) & 0xFFu], g4[v & 0xFFFFu]);
  }
  __syncthreads();
  int n = b*256 + t;
  if (n < N){
    float r = dis[n]*(g4[n] + a[t]) + b4f[0];
    if (*isf32) ((float*)out)[n] = r;
    else        ((u16*)out)[n]   = f2bf(r);
  }
}

extern "C" void kernel_launch(void* const* d_in, const int* in_sizes, int n_in,
                              void* d_out, int out_size, void* d_ws, size_t ws_size,
                              hipStream_t stream){
  const void* x0 = d_in[0];
  const u32*  ei = (const u32*)d_in[1];
  int N = in_sizes[0] / F;           // 50000
  int E = in_sizes[1] / 2;           // 1,600,000
  int NB = (N + 255) >> 8;           // 196 buckets
  int Npad = ((N + 63)/64)*64;       // k_mm zero-fills [N, Npad)

  char* base = (char*)d_ws;
  size_t off = 0;
  auto alloc = [&](size_t bytes)->char*{
    char* p = base + off;
    off = (off + bytes + 255) & ~(size_t)255;
    return p;
  };
  float* dis  = (float*)alloc((size_t)N*4);
  float* g4   = (float*)alloc((size_t)N*4);
  int*   bcnt = (int*)  alloc(1024);
  int*   bbase= (int*)  alloc(1056);               // 257 ints
  int*   bump = (int*)  alloc(1024);
  int*   flags= (int*)  alloc(256);                // [0]=int32-edge, [1]=isf32
  u32*   ebuf = (u32*)  alloc((size_t)E*4);        // 6.4 MB bucketed edges
  u16*   WL   = (u16*)  alloc((size_t)3*16384*2);  // 96 KB swizzled weights
  float* wf4  = (float*)alloc(F*4);
  float* bb   = (float*)alloc((size_t)3*F*4);
  float* bb4  = (float*)alloc(256);
  u16*   gbuf = (u16*)  alloc((size_t)Npad*F*2);   // 12.8 MB, 4 planes
  u16*   xbuf = (u16*)  alloc((size_t)Npad*F*2);   // 12.8 MB row-major

  int* eflag = flags + 0;
  int* isf32 = flags + 1;

  int etb = (E + 4095)/4096;
  int mmb = (N + 63)/64;
  int agb = ((NB + 1)/2)*8;          // (bucket, plane) blocks, XCD-pinned planes

  k_flags <<<1, 256, 0, stream>>>((const u32*)x0, ei, flags, bcnt);
  k_bhist <<<etb, 256, 0, stream>>>(ei, E, eflag, NB, bcnt);
  k_bscan <<<1, 256, 0, stream>>>(bcnt, NB, E, bbase, bump);
  k_msplit<<<etb, 256, 0, stream>>>(ei, E, eflag, bbase, bump, ebuf);
  k_bemit <<<NB, 256, 0, stream>>>(ebuf, bbase, N, dis, g4);
  k_prep  <<<193, 256, 0, stream>>>(d_in[2], d_in[4], d_in[6], d_in[8],
                                    d_in[3], d_in[5], d_in[7], d_in[9],
                                    isf32, WL, bb, wf4, bb4);

  // layer 1 (reads input directly, dual-dtype)
  k_mm     <<<mmb, 256, 0, stream>>>(x0, isf32, 1, WL, dis, gbuf, N, Npad);
  k_aggB<0><<<agb, 256, 0, stream>>>(gbuf, dis, bbase, ebuf, bb, wf4, g4, xbuf, N, NB, Npad);
  // layer 2
  k_mm     <<<mmb, 256, 0, stream>>>(xbuf, isf32, 0, WL + 16384, dis, gbuf, N, Npad);
  k_aggB<0><<<agb, 256, 0, stream>>>(gbuf, dis, bbase, ebuf, bb + F, wf4, g4, xbuf, N, NB, Npad);
  // layer 3 (+ fused layer-4 matmul into g4)
  k_mm     <<<mmb, 256, 0, stream>>>(xbuf, isf32, 0, WL + 32768, dis, gbuf, N, Npad);
  k_aggB<1><<<agb, 256, 0, stream>>>(gbuf, dis, bbase, ebuf, bb + 2*F, wf4, g4, xbuf, N, NB, Npad);
  // layer 4 aggregation
  k_agg4B  <<<NB, 256, 0, stream>>>(g4, dis, bbase, ebuf, bb4, isf32, (void*)d_out, N);
}

// Round 9
// 429.759 us; speedup vs baseline: 9.7536x; 9.7536x over previous
//
#include <hip/hip_runtime.h>
#include <hip/hip_bf16.h>
#include <stdint.h>

typedef unsigned int u32;
typedef unsigned short u16;

#define F 128

typedef __attribute__((ext_vector_type(8))) short bf16x8;
typedef __attribute__((ext_vector_type(4))) float f32x4;

__device__ __forceinline__ float bf2f(u16 v){
  union { u32 u; float f; } x; x.u = ((u32)v) << 16; return x.f;
}
__device__ __forceinline__ u16 f2bf(float f){
  union { float f; u32 u; } x; x.f = f;
  u32 u = x.u;
  return (u16)((u + 0x7fffu + ((u >> 16) & 1u)) >> 16);   // RNE
}

// flags[0]=edge-int32 flag, flags[1]=x-is-f32 flag; also zeroes bcnt.
__global__ void k_flags(const u32* __restrict__ x, const u32* __restrict__ ei,
                        int* __restrict__ flags, int* __restrict__ bcnt){
  __shared__ int f[2];
  int t = threadIdx.x;
  bcnt[t] = 0;
  if (t < 2) f[t] = 0;
  __syncthreads();
  int hit = 0;
  for (int i = t; i < 2048; i += 256){
    u32 e = (x[i] >> 7) & 0xFFu;          // f32 words: uniform bits[14:7]
    if (e > 160u) hit = 1;                // bf16-pair data never exceeds 160
  }
  if (hit) atomicOr(&f[1], 1);
  u32 v = 0;
  for (int i = t; i < 4096; i += 256) v |= ei[2*i + 1];  // int64 ids<50000 -> odd words 0
  if (v) atomicOr(&f[0], 1);
  __syncthreads();
  if (t < 2) flags[t] = f[t];
}

// ---- bucketed CSR build (256-node buckets) ----------------------------------
__launch_bounds__(256)
__global__ void k_bhist(const u32* __restrict__ w, int E, const int* __restrict__ flagp,
                        int NB, int* __restrict__ bcnt){
  __shared__ int h[256];
  int st = (*flagp) ? 1 : 2;
  int t = threadIdx.x;
  h[t] = 0;
  __syncthreads();
  int base = blockIdx.x*4096;
  #pragma unroll 4
  for (int k = 0; k < 16; k++){
    int i = base + k*256 + t;
    if (i < E){
      int d = (int)w[(size_t)(E + i)*st];
      atomicAdd(&h[d >> 8], 1);
    }
  }
  __syncthreads();
  if (t < NB && h[t]) atomicAdd(&bcnt[t], h[t]);
}

__global__ void k_bscan(const int* __restrict__ bcnt, int NB, int E,
                        int* __restrict__ bbase, int* __restrict__ bump){
  __shared__ int s[256];
  int t = threadIdx.x;
  int v = (t < NB) ? bcnt[t] : 0;
  s[t] = v;
  __syncthreads();
  for (int off = 1; off < 256; off <<= 1){
    int x = (t >= off) ? s[t - off] : 0;
    __syncthreads();
    s[t] += x;
    __syncthreads();
  }
  bbase[t] = s[t] - v;            // exclusive; == E for t >= NB
  if (t == 255) bbase[256] = E;
  bump[t] = 0;
}

__launch_bounds__(256)
__global__ void k_msplit(const u32* __restrict__ w, int E, const int* __restrict__ flagp,
                         const int* __restrict__ bbase, int* __restrict__ bump,
                         u32* __restrict__ ebuf){
  __shared__ int h[256];
  __shared__ int cb[256];
  int st = (*flagp) ? 1 : 2;
  int t = threadIdx.x;
  h[t] = 0;
  __syncthreads();
  int base = blockIdx.x*4096;
  u32 ps[16]; int bk[16]; int rk[16];
  #pragma unroll 4
  for (int k = 0; k < 16; k++){
    int i = base + k*256 + t;
    if (i < E){
      u32 s = w[(size_t)i*st];
      u32 d = w[(size_t)(E + i)*st];
      bk[k] = (int)(d >> 8);
      ps[k] = (s & 0xFFFFu) | ((d & 0xFFu) << 16);
      rk[k] = atomicAdd(&h[bk[k]], 1);
    } else bk[k] = -1;
  }
  __syncthreads();
  cb[t] = h[t] ? (bbase[t] + atomicAdd(&bump[t], h[t])) : 0;
  __syncthreads();
  #pragma unroll 4
  for (int k = 0; k < 16; k++){
    if (bk[k] >= 0) ebuf[cb[bk[k]] + rk[k]] = ps[k];
  }
}

// Per-bucket deg/rs/csr emit (+ dis, + g4 zero); scatter stays L2-hot.
__launch_bounds__(256)
__global__ void k_bemit(const u32* __restrict__ ebuf, const int* __restrict__ bbase,
                        int N, int* __restrict__ deg, int* __restrict__ rs,
                        float* __restrict__ dis, float* __restrict__ g4,
                        u16* __restrict__ csr){
  __shared__ int nd[256];
  __shared__ int nofs[256];
  __shared__ int s[256];
  int b = blockIdx.x;
  int t = threadIdx.x;
  int e0 = bbase[b], e1 = bbase[b + 1];
  nd[t] = 0;
  __syncthreads();
  for (int i = e0 + t; i < e1; i += 256) atomicAdd(&nd[ebuf[i] >> 16], 1);
  __syncthreads();
  int v = nd[t];
  s[t] = v;
  __syncthreads();
  for (int off = 1; off < 256; off <<= 1){
    int x = (t >= off) ? s[t - off] : 0;
    __syncthreads();
    s[t] += x;
    __syncthreads();
  }
  nofs[t] = s[t] - v;
  int node = b*256 + t;
  if (node < N){
    deg[node] = v;
    rs[node]  = e0 + nofs[t];
    dis[node] = rsqrtf(1.0f + (float)v);
    g4[node]  = 0.f;
  }
  nd[t] = 0;               // reuse as fill
  __syncthreads();
  for (int i = e0 + t; i < e1; i += 256){
    u32 p = ebuf[i];
    int d = (int)(p >> 16);
    int pos = e0 + nofs[d] + atomicAdd(&nd[d], 1);
    csr[pos] = (u16)(p & 0xFFFFu);
  }
}

// One-shot weight prep: 3x swizzled W (MFMA B-frag order) + 3 biases + W4 + b4.
__global__ void k_prep(const void* __restrict__ W1, const void* __restrict__ W2,
                       const void* __restrict__ W3, const void* __restrict__ W4,
                       const void* __restrict__ b1, const void* __restrict__ b2,
                       const void* __restrict__ b3, const void* __restrict__ b4,
                       const int* __restrict__ isf32, u16* __restrict__ WL,
                       float* __restrict__ bb, float* __restrict__ wf4,
                       float* __restrict__ bb4){
  int b = blockIdx.x, t = threadIdx.x;
  int f32 = *isf32;
  if (b < 192){
    int l = b >> 6;
    const void* W = (l == 0) ? W1 : (l == 1) ? W2 : W3;
    int idx = (b & 63)*256 + t;          // 0..16383
    int j    = idx & 7;
    int lane = (idx >> 3) & 63;
    int kb   = (idx >> 9) & 3;
    int ct   = idx >> 11;
    int m = lane & 15, q = lane >> 4;
    int k = kb*32 + q*8 + j;
    int c = ct*16 + m;
    float v = f32 ? ((const float*)W)[k*F + c] : bf2f(((const u16*)W)[k*F + c]);
    WL[l*16384 + idx] = f2bf(v);
  } else {
    if (t < 128){
      const void* bs[3] = {b1, b2, b3};
      #pragma unroll
      for (int l = 0; l < 3; l++)
        bb[l*F + t] = f32 ? ((const float*)bs[l])[t] : bf2f(((const u16*)bs[l])[t]);
      wf4[t] = f32 ? ((const float*)W4)[t] : bf2f(((const u16*)W4)[t]);
      if (t == 0) bb4[0] = f32 ? ((const float*)b4)[0] : bf2f(((const u16*)b4)[0]);
    }
  }
}

// G = dis * (X @ W) stored as 4 contiguous planes (plane = 32 feats x Npad rows,
// 64 B/row, 3.2 MB -> per-XCD L2 resident). Rows [N, Npad) zero-filled.
__launch_bounds__(256)
__global__ void k_mm(const void* __restrict__ Xv, const int* __restrict__ isf32,
                     int dual, const u16* __restrict__ WL,
                     const float* __restrict__ dis, u16* __restrict__ G,
                     int N, int Npad){
  int w = threadIdx.x >> 6, lane = threadIdx.x & 63;
  int m = lane & 15, q = lane >> 4;
  int row0 = blockIdx.x*64 + w*16;
  int arow = row0 + m;
  bool f32 = dual && (*isf32);
  bf16x8 a[4];
  if (arow < N){
    if (f32){
      const float* xp = (const float*)Xv + (size_t)arow*F;
      #pragma unroll
      for (int kb = 0; kb < 4; kb++){
        float4 v0 = *(const float4*)(xp + kb*32 + q*8);
        float4 v1 = *(const float4*)(xp + kb*32 + q*8 + 4);
        a[kb][0] = (short)f2bf(v0.x); a[kb][1] = (short)f2bf(v0.y);
        a[kb][2] = (short)f2bf(v0.z); a[kb][3] = (short)f2bf(v0.w);
        a[kb][4] = (short)f2bf(v1.x); a[kb][5] = (short)f2bf(v1.y);
        a[kb][6] = (short)f2bf(v1.z); a[kb][7] = (short)f2bf(v1.w);
      }
    } else {
      const u16* xp = (const u16*)Xv + (size_t)arow*F;
      #pragma unroll
      for (int kb = 0; kb < 4; kb++) a[kb] = *(const bf16x8*)(xp + kb*32 + q*8);
    }
  } else {
    #pragma unroll
    for (int kb = 0; kb < 4; kb++) a[kb] = (bf16x8){0,0,0,0,0,0,0,0};
  }
  f32x4 acc[8];
  #pragma unroll
  for (int ct = 0; ct < 8; ct++) acc[ct] = (f32x4){0.f,0.f,0.f,0.f};
  #pragma unroll
  for (int ct = 0; ct < 8; ct++){
    #pragma unroll
    for (int kb = 0; kb < 4; kb++){
      bf16x8 b = *(const bf16x8*)(WL + ((size_t)((ct*4 + kb)*64 + lane))*8);
      acc[ct] = __builtin_amdgcn_mfma_f32_16x16x32_bf16(a[kb], b, acc[ct], 0, 0, 0);
    }
  }
  size_t planeW = (size_t)Npad*32;       // u16 elements per plane
  int rbase = row0 + q*4;
  #pragma unroll
  for (int r = 0; r < 4; r++){
    int row = rbase + r;
    float dv = (row < N) ? dis[row] : 0.f;      // pad rows -> zeros
    #pragma unroll
    for (int ct = 0; ct < 8; ct++){
      int p = ct >> 1, h = ct & 1;
      G[p*planeW + (size_t)row*32 + h*16 + m] = f2bf(dv*acc[ct][r]);
    }
  }
}

// Chunked aggregation over contiguous planes, 8-deep ILP, XCD-PINNED planes:
// plane = (blockIdx&7)>>1 so each XCD (heuristic: blocks round-robin by id%8)
// sees exactly one 3.2MB plane -> plane stays L2-resident, gathers are L2 hits.
// Wave = 1 node; 16 lanes/edge-row; 32-edge blocks: 8 shfls, 8 loads, 16 adds.
// LAST=1: fuse layer-4 dot (atomicAdd into g4), skip Xout store.
template<int LAST>
__launch_bounds__(256)
__global__ void k_agg(const u16* __restrict__ G, const float* __restrict__ dis,
                      const int* __restrict__ rs, const int* __restrict__ deg,
                      const u16* __restrict__ csr, const float* __restrict__ bias,
                      u16* __restrict__ Xout, const float* __restrict__ wf4,
                      float* __restrict__ g4, int N, int Npad, int NblkX){
  const u32* Gw = (const u32*)G;
  u32* Xw = (u32*)Xout;
  int b = blockIdx.x;
  int x = b & 7;
  int c = x >> 1;                                // plane 0..3 (XCD-pinned)
  int nblk = ((b >> 3) << 1) + (x & 1);          // node-block 0..NblkX-1
  if (nblk >= NblkX) return;
  int wid  = nblk*4 + (threadIdx.x >> 6);
  int lane = threadIdx.x & 63;
  if (wid >= N) return;
  int g    = lane >> 4;
  int w16  = lane & 15;
  const u32* P = Gw + (size_t)c*((size_t)Npad*16);
  int base = rs[wid], len = deg[wid];
  float a0 = 0.f, a1 = 0.f;
  for (int c0 = 0; c0 < len; c0 += 64){
    int mm = len - c0; if (mm > 64) mm = 64;
    int sidx = (lane < mm) ? (int)csr[base + c0 + lane] : N;   // N = zero pad row
    int nb2 = (mm + 31) >> 5;
    for (int jb = 0; jb < nb2; jb++){
      u32 wv[8];
      #pragma unroll
      for (int u = 0; u < 8; u++){
        int s = __shfl(sidx, (jb*8 + u)*4 + g, 64);
        wv[u] = P[((size_t)(u32)s << 4) + w16];
      }
      #pragma unroll
      for (int u = 0; u < 8; u++){
        a0 += __uint_as_float(wv[u] << 16);
        a1 += __uint_as_float(wv[u] & 0xFFFF0000u);
      }
    }
  }
  a0 += __shfl_xor(a0, 16, 64); a0 += __shfl_xor(a0, 32, 64);
  a1 += __shfl_xor(a1, 16, 64); a1 += __shfl_xor(a1, 32, 64);
  if (lane < 16){
    u32 sw = P[((size_t)wid << 4) + w16];
    float dv = dis[wid];
    float o0 = fmaf(dv, __uint_as_float(sw << 16) + a0, bias[c*32 + 2*w16]);
    float o1 = fmaf(dv, __uint_as_float(sw & 0xFFFF0000u) + a1, bias[c*32 + 2*w16 + 1]);
    o0 = fmaxf(o0, 0.f); o1 = fmaxf(o1, 0.f);
    if (LAST){
      float part = o0*wf4[c*32 + 2*w16] + o1*wf4[c*32 + 2*w16 + 1];
      part += __shfl_xor(part, 1, 64);
      part += __shfl_xor(part, 2, 64);
      part += __shfl_xor(part, 4, 64);
      part += __shfl_xor(part, 8, 64);
      if (lane == 0) atomicAdd(&g4[wid], dv*part);
    } else {
      Xw[((size_t)wid << 6) + c*16 + w16] = (u32)f2bf(o0) | ((u32)f2bf(o1) << 16);
    }
  }
}

// final aggregation: wave per node, 64 parallel 4B gathers from L2-hot g4.
__launch_bounds__(256)
__global__ void k_agg4(const float* __restrict__ G4, const float* __restrict__ dis,
                       const int* __restrict__ rs, const int* __restrict__ deg,
                       const u16* __restrict__ csr, const float* __restrict__ b4f,
                       const int* __restrict__ isf32, void* __restrict__ out, int N){
  int wid  = blockIdx.x*4 + (threadIdx.x >> 6);
  int lane = threadIdx.x & 63;
  if (wid >= N) return;
  int base = rs[wid], len = deg[wid];
  float acc = 0.f;
  for (int j = lane; j < len; j += 64) acc += G4[csr[base + j]];
  #pragma unroll
  for (int off = 32; off > 0; off >>= 1) acc += __shfl_down(acc, off, 64);
  if (lane == 0){
    float r = dis[wid]*(G4[wid] + acc) + b4f[0];
    if (*isf32) ((float*)out)[wid] = r;
    else        ((u16*)out)[wid]   = f2bf(r);
  }
}

extern "C" void kernel_launch(void* const* d_in, const int* in_sizes, int n_in,
                              void* d_out, int out_size, void* d_ws, size_t ws_size,
                              hipStream_t stream){
  const void* x0 = d_in[0];
  const u32*  ei = (const u32*)d_in[1];
  int N = in_sizes[0] / F;           // 50000
  int E = in_sizes[1] / 2;           // 1,600,000
  int NB = (N + 255) >> 8;           // 196 buckets
  int Npad = ((N + 63)/64)*64;       // k_mm zero-fills [N, Npad)

  char* base = (char*)d_ws;
  size_t off = 0;
  auto alloc = [&](size_t bytes)->char*{
    char* p = base + off;
    off = (off + bytes + 255) & ~(size_t)255;
    return p;
  };
  int*   deg  = (int*)  alloc((size_t)N*4);
  float* dis  = (float*)alloc((size_t)N*4);
  int*   rs   = (int*)  alloc((size_t)N*4);
  float* g4   = (float*)alloc((size_t)N*4);
  int*   bcnt = (int*)  alloc(1024);
  int*   bbase= (int*)  alloc(1056);               // 257 ints
  int*   bump = (int*)  alloc(1024);
  int*   flags= (int*)  alloc(256);                // [0]=int32-edge, [1]=isf32
  u32*   ebuf = (u32*)  alloc((size_t)E*4);        // 6.4 MB
  u16*   csr  = (u16*)  alloc((size_t)E*2);        // 3.2 MB
  u16*   WL   = (u16*)  alloc((size_t)3*16384*2);  // 96 KB swizzled weights
  float* wf4  = (float*)alloc(F*4);
  float* bb   = (float*)alloc((size_t)3*F*4);
  float* bb4  = (float*)alloc(256);
  u16*   gbuf = (u16*)  alloc((size_t)Npad*F*2);   // 12.8 MB, 4 planes
  u16*   xbuf = (u16*)  alloc((size_t)Npad*F*2);   // 12.8 MB row-major

  int* eflag = flags + 0;
  int* isf32 = flags + 1;

  int etb = (E + 4095)/4096;
  int mmb = (N + 63)/64;
  int NblkX = (N + 3)/4;             // node-blocks (4 nodes per block)
  int agb = ((NblkX + 1)/2)*8;       // (node-block, plane) with XCD-pinned planes

  k_flags <<<1, 256, 0, stream>>>((const u32*)x0, ei, flags, bcnt);
  k_bhist <<<etb, 256, 0, stream>>>(ei, E, eflag, NB, bcnt);
  k_bscan <<<1, 256, 0, stream>>>(bcnt, NB, E, bbase, bump);
  k_msplit<<<etb, 256, 0, stream>>>(ei, E, eflag, bbase, bump, ebuf);
  k_bemit <<<NB, 256, 0, stream>>>(ebuf, bbase, N, deg, rs, dis, g4, csr);
  k_prep  <<<193, 256, 0, stream>>>(d_in[2], d_in[4], d_in[6], d_in[8],
                                    d_in[3], d_in[5], d_in[7], d_in[9],
                                    isf32, WL, bb, wf4, bb4);

  // layer 1 (reads input directly, dual-dtype)
  k_mm    <<<mmb, 256, 0, stream>>>(x0, isf32, 1, WL, dis, gbuf, N, Npad);
  k_agg<0><<<agb, 256, 0, stream>>>(gbuf, dis, rs, deg, csr, bb, xbuf, wf4, g4, N, Npad, NblkX);
  // layer 2
  k_mm    <<<mmb, 256, 0, stream>>>(xbuf, isf32, 0, WL + 16384, dis, gbuf, N, Npad);
  k_agg<0><<<agb, 256, 0, stream>>>(gbuf, dis, rs, deg, csr, bb + F, xbuf, wf4, g4, N, Npad, NblkX);
  // layer 3 (+ fused layer-4 matmul into g4)
  k_mm    <<<mmb, 256, 0, stream>>>(xbuf, isf32, 0, WL + 32768, dis, gbuf, N, Npad);
  k_agg<1><<<agb, 256, 0, stream>>>(gbuf, dis, rs, deg, csr, bb + 2*F, xbuf, wf4, g4, N, Npad, NblkX);
  // layer 4 aggregation
  k_agg4  <<<(N + 3)/4, 256, 0, stream>>>(g4, dis, rs, deg, csr, bb4, isf32, (void*)d_out, N);
}